// Round 15
// baseline (43.780 us; speedup 1.0000x reference)
//
#include <hip/hip_runtime.h>

#define NCLUSTER 512
#define NC 3
#define HW 65536
#define GRID1 16                      // grid cells per dim
#define NCELL (GRID1*GRID1*GRID1)     // 4096
#define RANGE 4.0f
#define INV_H 2.0f                    // 1/cell = 2
#define BLOCK 256
#define NW 4
#define EPS 1e-4f                     // certified gap (validated R8-R14)
#define TBMARGIN 1e-2f                // safety margin on geometric bound

// ws layout: [0] float4 sortedC[512] | [8192] u16 origId[512] | [9216] u16 cellStart[4097]
// Phase 1: per-px 27-cell candidate scan + geometric bound + EPS certification.
// Phase 2: uncertified px -> wave-coop full-512 certified fp32 scan.
// Phase 3: EPS-near-ties -> wave-coop exact fp64 resolve (absmax-0 machinery).

__global__ __launch_bounds__(512) void kmeans_build(
    const float* __restrict__ C, void* __restrict__ ws)
{
    float4* sortedC = (float4*)ws;
    ushort* origId  = (ushort*)((char*)ws + 8192);
    ushort* cellSt  = (ushort*)((char*)ws + 9216);

    __shared__ int cnt[NCELL];     // 16 KB
    __shared__ int start[NCELL];   // 16 KB
    __shared__ int part[512];
    const int t = threadIdx.x;
#pragma unroll
    for (int i = 0; i < NCELL/512; ++i) cnt[t + i*512] = 0;
    __syncthreads();

    int mycell = 0; float c0 = 0, c1 = 0, c2 = 0;
    if (t < NCLUSTER) {
        c0 = C[t*NC+0]; c1 = C[t*NC+1]; c2 = C[t*NC+2];
        // clamp: out-of-range clusters land in edge cells; safe (they are
        // farther than the nominal box, bound direction preserved)
        int ci = min(max((int)floorf((c0+RANGE)*INV_H), 0), GRID1-1);
        int cj = min(max((int)floorf((c1+RANGE)*INV_H), 0), GRID1-1);
        int ck = min(max((int)floorf((c2+RANGE)*INV_H), 0), GRID1-1);
        mycell = (ci*GRID1 + cj)*GRID1 + ck;
        atomicAdd(&cnt[mycell], 1);
    }
    __syncthreads();
    int s = 0;
#pragma unroll
    for (int i = 0; i < 8; ++i) s += cnt[t*8+i];
    part[t] = s;
    __syncthreads();
    for (int d = 1; d < 512; d <<= 1) {          // Hillis-Steele inclusive scan
        int v = (t >= d) ? part[t-d] : 0;
        __syncthreads();
        part[t] += v;
        __syncthreads();
    }
    int run = (t == 0) ? 0 : part[t-1];
#pragma unroll
    for (int i = 0; i < 8; ++i) { start[t*8+i] = run; run += cnt[t*8+i]; }
    __syncthreads();
#pragma unroll
    for (int i = 0; i < 8; ++i) cellSt[t*8+i] = (ushort)start[t*8+i];
    if (t == 0) cellSt[NCELL] = (ushort)NCLUSTER;
#pragma unroll
    for (int i = 0; i < NCELL/512; ++i) cnt[t + i*512] = 0;
    __syncthreads();
    if (t < NCLUSTER) {
        int r = atomicAdd(&cnt[mycell], 1);
        int pos = start[mycell] + r;
        double d0 = c0, d1 = c1, d2 = c2;
        sortedC[pos] = make_float4(c0, c1, c2,
                                   (float)(0.5*(d0*d0 + d1*d1 + d2*d2)));
        origId[pos] = (ushort)t;
    }
}

__global__ __launch_bounds__(BLOCK) void kmeans_assign(
    const float* __restrict__ x, const void* __restrict__ ws,
    int* __restrict__ out)
{
    const float4* g_sc  = (const float4*)ws;
    const uint*   g_oid = (const uint*)((const char*)ws + 8192);
    const uint*   g_cs  = (const uint*)((const char*)ws + 9216);

    __shared__ float4 lcS[NCLUSTER];      // 8 KB  sorted clusters {c0,c1,c2,w}
    __shared__ ushort oid[NCLUSTER];      // 1 KB  sorted -> original id
    __shared__ ushort cst[NCELL+2];       // 8.2 KB CSR starts
    __shared__ int qpx[BLOCK], q2[BLOCK];
    __shared__ int qcnt, q2cnt;

    const int tid = threadIdx.x;
    if (tid == 0) { qcnt = 0; q2cnt = 0; }
#pragma unroll
    for (int i = 0; i < 2; ++i) {
        int k = tid + i*BLOCK;
        lcS[k] = g_sc[k];
        ((uint*)oid)[tid + i*BLOCK & 0xFFFF] = 0;  // placeholder overwritten below
    }
    // oid: 512 u16 = 256 u32; cst: 4098 u16 = 2049 u32
    ((uint*)oid)[tid] = g_oid[tid];
    for (int k = tid; k < 2049; k += BLOCK) ((uint*)cst)[k] = g_cs[k];

    const int B0 = blockIdx.x * BLOCK;
    const int gpx = B0 + tid;
    const int p = gpx & (HW-1);
    const float* xb = x + (size_t)(gpx >> 16) * NC * HW;
    float x0 = xb[p], x1 = xb[p+HW], x2 = xb[p+2*HW];
    float S = __builtin_fmaf(x0, x0, __builtin_fmaf(x1, x1, x2*x2));
    __syncthreads();

    // ---- phase 1: 27-cell candidate scan ----
    float b1 = 1e30f, b2 = 1e30f;
    int idq = 0;                     // sorted-space index (ties never published)
    bool oob = (fabsf(x0) >= 3.999f) | (fabsf(x1) >= 3.999f) | (fabsf(x2) >= 3.999f);
    bool ok = false;
    if (!oob) {
        int ci = (int)floorf((x0+RANGE)*INV_H);
        int cj = (int)floorf((x1+RANGE)*INV_H);
        int ck = (int)floorf((x2+RANGE)*INV_H);
#pragma unroll
        for (int dx = -1; dx <= 1; ++dx) {
#pragma unroll
            for (int dy = -1; dy <= 1; ++dy) {
#pragma unroll
                for (int dz = -1; dz <= 1; ++dz) {
                    int ii = ci+dx, jj = cj+dy, kk = ck+dz;
                    if ((unsigned)ii < GRID1 && (unsigned)jj < GRID1 &&
                        (unsigned)kk < GRID1) {
                        int cell = (ii*GRID1 + jj)*GRID1 + kk;
                        int qs = cst[cell], qe = cst[cell+1];
                        for (int q = qs; q < qe; ++q) {
                            float4 c = lcS[q];
                            float t = __builtin_fmaf(-x0, c.x, c.w);
                            t = __builtin_fmaf(-x1, c.y, t);
                            t = __builtin_fmaf(-x2, c.z, t);
                            bool lt = t < b1;
                            b2 = __builtin_amdgcn_fmed3f(t, b1, b2);
                            idq = lt ? q : idq;
                            b1 = fminf(t, b1);
                        }
                    }
                }
            }
        }
        // unscanned clusters: coord gap >= 0.5 => t >= (0.25 - S)/2
        float tb = 0.5f*(0.25f - S) - TBMARGIN;
        ok = (b2 - b1 >= EPS) && (tb >= b1 + EPS);
    }
    if (ok) out[gpx] = (int)oid[idq];
    else qpx[atomicAdd(&qcnt, 1)] = tid;
    __syncthreads();

    // ---- phase 2: full-512 certified fp32 scan, one queued px per wave ----
    const int w = tid >> 6, l = tid & 63;
    const int n1 = qcnt;
    for (int e = w; e < n1; e += NW) {
        const int t = qpx[e];
        const int gq = B0 + t;
        const int pq = gq & (HW-1);
        const float* xq = x + (size_t)(gq >> 16) * NC * HW;
        float y0 = xq[pq], y1 = xq[pq+HW], y2 = xq[pq+2*HW];
        float pb1 = 1e30f, pb2 = 1e30f;
        int pid = 0x7fffffff;
#pragma unroll
        for (int j = 0; j < NCLUSTER/64; ++j) {
            int q = j*64 + l;
            float4 c = lcS[q];
            int kid = oid[q];
            float tt = __builtin_fmaf(-y0, c.x, c.w);
            tt = __builtin_fmaf(-y1, c.y, tt);
            tt = __builtin_fmaf(-y2, c.z, tt);
            bool bet = (tt < pb1) || (tt == pb1 && kid < pid);
            pb2 = __builtin_amdgcn_fmed3f(tt, pb1, pb2);
            pid = bet ? kid : pid;
            pb1 = fminf(tt, pb1);
        }
#pragma unroll
        for (int m = 1; m < 64; m <<= 1) {
            float ob1 = __shfl_xor(pb1, m, 64);
            float ob2 = __shfl_xor(pb2, m, 64);
            int opid  = __shfl_xor(pid, m, 64);
            pb2 = fminf(fminf(pb2, ob2), fmaxf(pb1, ob1));  // exact union 2nd-best
            bool take = (ob1 < pb1) || (ob1 == pb1 && opid < pid);
            pid = take ? opid : pid;
            pb1 = fminf(pb1, ob1);
        }
        if (pb2 - pb1 >= EPS) {
            if (l == 0) out[gq] = pid;
        } else {
            if (l == 0) q2[atomicAdd(&q2cnt, 1)] = t;
        }
    }
    __syncthreads();

    // ---- phase 3: exact fp64 resolve (validated absmax 0), smallest-k ties ----
    const int n2 = q2cnt;
    for (int e = w; e < n2; e += NW) {
        const int t = q2[e];
        const int gq = B0 + t;
        const int pq = gq & (HW-1);
        const float* xq = x + (size_t)(gq >> 16) * NC * HW;
        double X0 = xq[pq], X1 = xq[pq+HW], X2 = xq[pq+2*HW];
        double bd = 1e300;
        int bi = 0x7fffffff;
#pragma unroll
        for (int j = 0; j < NCLUSTER/64; ++j) {
            int q = j*64 + l;
            float4 c = lcS[q];
            int kid = oid[q];
            double d0 = X0 - (double)c.x;
            double d1 = X1 - (double)c.y;
            double d2 = X2 - (double)c.z;
            double d = d0*d0 + d1*d1 + d2*d2;
            if (d < bd || (d == bd && kid < bi)) { bd = d; bi = kid; }
        }
#pragma unroll
        for (int m = 1; m < 64; m <<= 1) {
            double od = __shfl_xor(bd, m, 64);
            int oi = __shfl_xor(bi, m, 64);
            bool take = (od < bd) || (od == bd && oi < bi);
            bd = take ? od : bd;
            bi = take ? oi : bi;
        }
        if (l == 0) out[gq] = bi;
    }
}

extern "C" void kernel_launch(void* const* d_in, const int* in_sizes, int n_in,
                              void* d_out, int out_size, void* d_ws, size_t ws_size,
                              hipStream_t stream) {
    const float* x = (const float*)d_in[0];
    const float* C = (const float*)d_in[1];
    int* out = (int*)d_out;

    kmeans_build<<<1, 512, 0, stream>>>(C, d_ws);

    int total = out_size;              // 262144
    int grid = total / BLOCK;          // 1024 blocks -> 16 waves/CU
    kmeans_assign<<<grid, BLOCK, 0, stream>>>(x, d_ws, out);
}